// Round 1
// 242.612 us; speedup vs baseline: 1.0340x; 1.0340x over previous
//
#include <hip/hip_runtime.h>
#include <stdint.h>

// Problem geometry (fixed by reference):
//   logits [8,4096,1024] f32, primitives [1024,1024] f32
//   outputs: embeddings [8,4096,1024] f32 | indices [8,4096] (as f32) | counts [1024] (as f32)
#define NROWS   32768        // 8*4096
#define KDIM    1024
#define IDX_OFF 33554432     // 8*4096*1024
#define CNT_OFF 33587200     // IDX_OFF + 32768

__device__ __forceinline__ uint32_t rotl32(uint32_t x, int r) {
    return (x << r) | (x >> (32 - r));
}

// threefry2x32-20 with key (k0=0, k1=42), input words (x0=0, x1=ctr).
// Returns o0 ^ o1 — JAX partitionable 32-bit random_bits. Bit-exact, irreducible.
__device__ __forceinline__ uint32_t threefry_bits(uint32_t ctr) {
    const uint32_t ks0 = 0u;
    const uint32_t ks1 = 42u;
    const uint32_t ks2 = 0x1BD11BDAu ^ 0u ^ 42u;   // 0x1BD11BF0

    uint32_t x0 = 0u + ks0;
    uint32_t x1 = ctr + ks1;

    // group 0: rotations 13,15,26,6
    x0 += x1; x1 = rotl32(x1, 13); x1 ^= x0;
    x0 += x1; x1 = rotl32(x1, 15); x1 ^= x0;
    x0 += x1; x1 = rotl32(x1, 26); x1 ^= x0;
    x0 += x1; x1 = rotl32(x1,  6); x1 ^= x0;
    x0 += ks1; x1 += ks2 + 1u;
    // group 1: rotations 17,29,16,24
    x0 += x1; x1 = rotl32(x1, 17); x1 ^= x0;
    x0 += x1; x1 = rotl32(x1, 29); x1 ^= x0;
    x0 += x1; x1 = rotl32(x1, 16); x1 ^= x0;
    x0 += x1; x1 = rotl32(x1, 24); x1 ^= x0;
    x0 += ks2; x1 += ks0 + 2u;
    // group 2: rotations 13,15,26,6
    x0 += x1; x1 = rotl32(x1, 13); x1 ^= x0;
    x0 += x1; x1 = rotl32(x1, 15); x1 ^= x0;
    x0 += x1; x1 = rotl32(x1, 26); x1 ^= x0;
    x0 += x1; x1 = rotl32(x1,  6); x1 ^= x0;
    x0 += ks0; x1 += ks1 + 3u;
    // group 3: rotations 17,29,16,24
    x0 += x1; x1 = rotl32(x1, 17); x1 ^= x0;
    x0 += x1; x1 = rotl32(x1, 29); x1 ^= x0;
    x0 += x1; x1 = rotl32(x1, 16); x1 ^= x0;
    x0 += x1; x1 = rotl32(x1, 24); x1 ^= x0;
    x0 += ks1; x1 += ks2 + 4u;
    // group 4: rotations 13,15,26,6
    x0 += x1; x1 = rotl32(x1, 13); x1 ^= x0;
    x0 += x1; x1 = rotl32(x1, 15); x1 ^= x0;
    x0 += x1; x1 = rotl32(x1, 26); x1 ^= x0;
    x0 += x1; x1 = rotl32(x1,  6); x1 ^= x0;
    x0 += ks2; x1 += ks0 + 5u;

    return x0 ^ x1;
}

// Ordering-equivalent gumbel score in the log2 domain:
//   z = l + g,  g = -ln(-ln u)   ==>   z/ln2 = l*(1/ln2) - log2(-log2 u) + const
// so argmax over k is preserved (up to ~6e-7 fp noise vs the reference's own
// ~2e-7 — gap between top-2 is Exp(1), flip risk ~1%, same class as current).
//
// Inner -log2(u) needs RELATIVE accuracy where winners live (u -> 1: hw
// v_log_f32 has ~2^-22 ABSOLUTE error there, catastrophic relative error on a
// tiny result). Degree-7 Taylor in w = u-1 for u in [0.875,1): alternating
// series, truncation <= 6.4e-8 relative at |w|=0.125; w and u-1 are exact
// (Sterbenz). Hardware log elsewhere (t >= 0.19, error stays ~1e-6 absolute in
// the score — decisive comparisons essentially never involve that region).
__device__ __forceinline__ float score_from_bits(uint32_t bits, float logit) {
    float v1 = __uint_as_float((bits >> 9) | 0x3f800000u);  // [1,2)
    float f  = v1 - 1.0f;                                   // [0,1) exact
    float u  = fmaxf(f, 1.17549435e-38f);                   // matches JAX uniform
    float w  = u - 1.0f;                                    // exact for u >= 0.5
    // Q(w) = (1/ln2)*(-1 + w/2 - w^2/3 + w^3/4 - w^4/5 + w^5/6 - w^6/7)
    float q;
    q = fmaf(w, -0.20609929f,  0.24044917f);
    q = fmaf(w, q, -0.28853901f);
    q = fmaf(w, q,  0.36067376f);
    q = fmaf(w, q, -0.48089835f);
    q = fmaf(w, q,  0.72134752f);
    q = fmaf(w, q, -1.44269504f);
    float tp = w * q;                                       // -log2(u), u near 1
    float th = -__builtin_amdgcn_logf(u);                   // -log2(u), hw path
    float t  = (u >= 0.875f) ? tp : th;                     // t > 0 always
    float lg = __builtin_amdgcn_logf(t);                    // log2(-log2 u)
    return fmaf(logit, 1.44269504f, -lg);                   // z' = l/ln2 - lg
}

__global__ __launch_bounds__(256) void gumbel_argmax_gather(
    const float* __restrict__ logits,
    const float* __restrict__ prim,
    float* __restrict__ out)
{
    const int row = blockIdx.x;          // 0..32767 = b*4096+s, row-major flat
    const int tid = threadIdx.x;         // 0..255
    const uint32_t base = (uint32_t)row * (uint32_t)KDIM;
    const uint32_t k0   = 4u * (uint32_t)tid;   // 4 contiguous k per thread

    // single float4 logits load per thread (wave covers 4KB contiguous)
    const float4 l4 = *reinterpret_cast<const float4*>(logits + base + k0);
    const float lv[4] = {l4.x, l4.y, l4.z, l4.w};

    // --- per-thread argmax over 4 contiguous columns (ascending k: first-index ties kept)
    float bv = -INFINITY;
    int   bk = 0;
    #pragma unroll
    for (int m = 0; m < 4; ++m) {
        const float z = score_from_bits(threefry_bits(base + k0 + (uint32_t)m), lv[m]);
        if (z > bv) { bv = z; bk = (int)k0 + m; }
    }

    // --- wave (64-lane) reduction, first-index tie-break (lane order == k order)
    #pragma unroll
    for (int off = 32; off > 0; off >>= 1) {
        const float ov = __shfl_down(bv, off);
        const int   ok = __shfl_down(bk, off);
        if (ov > bv || (ov == bv && ok < bk)) { bv = ov; bk = ok; }
    }

    __shared__ float s_v[4];
    __shared__ int   s_k[4];
    __shared__ int   s_idx;
    const int wave = tid >> 6;
    if ((tid & 63) == 0) { s_v[wave] = bv; s_k[wave] = bk; }
    __syncthreads();

    if (tid == 0) {
        float v = s_v[0]; int kk = s_k[0];
        #pragma unroll
        for (int w = 1; w < 4; ++w) {
            if (s_v[w] > v || (s_v[w] == v && s_k[w] < kk)) { v = s_v[w]; kk = s_k[w]; }
        }
        s_idx = kk;
        out[IDX_OFF + row] = (float)kk;            // indices stored as f32 values
        atomicAdd(out + CNT_OFF + kk, 1.0f);       // exact integer accumulation in f32
    }
    __syncthreads();

    // --- gather primitives[idx] row -> embeddings row (float4, fully coalesced)
    const int idx = s_idx;
    const float4* __restrict__ src = (const float4*)(prim + (size_t)idx * KDIM);
    float4* __restrict__ dst = (float4*)(out + (size_t)row * KDIM);
    dst[tid] = src[tid];
}

extern "C" void kernel_launch(void* const* d_in, const int* in_sizes, int n_in,
                              void* d_out, int out_size, void* d_ws, size_t ws_size,
                              hipStream_t stream) {
    const float* logits = (const float*)d_in[0];   // [8,4096,1024] f32
    const float* prim   = (const float*)d_in[1];   // [1024,1024]   f32
    float* out = (float*)d_out;
    (void)d_ws; (void)ws_size; (void)in_sizes; (void)n_in; (void)out_size;

    // counts accumulate via f32 atomics directly in the output region:
    // zero it every launch (out is not re-initialized between iterations),
    // then one fused kernel — the counts_to_float dispatch is gone.
    hipMemsetAsync(out + CNT_OFF, 0, KDIM * sizeof(float), stream);
    gumbel_argmax_gather<<<NROWS, 256, 0, stream>>>(logits, prim, out);
}

// Round 2
// 235.642 us; speedup vs baseline: 1.0646x; 1.0296x over previous
//
#include <hip/hip_runtime.h>
#include <stdint.h>

// Problem geometry (fixed by reference):
//   logits [8,4096,1024] f32, primitives [1024,1024] f32
//   outputs: embeddings [8,4096,1024] f32 | indices [8,4096] (as f32) | counts [1024] (as f32)
#define NROWS   32768        // 8*4096
#define KDIM    1024
#define IDX_OFF 33554432     // 8*4096*1024
#define CNT_OFF 33587200     // IDX_OFF + 32768

__device__ __forceinline__ uint32_t rotl32(uint32_t x, int r) {
    return (x << r) | (x >> (32 - r));   // -> v_alignbit_b32
}

// threefry2x32-20 with key (k0=0, k1=42), input words (x0=0, x1=ctr).
// Returns o0 ^ o1 — JAX partitionable 32-bit random_bits. Bit-exact, irreducible.
__device__ __forceinline__ uint32_t threefry_bits(uint32_t ctr) {
    const uint32_t ks0 = 0u;
    const uint32_t ks1 = 42u;
    const uint32_t ks2 = 0x1BD11BDAu ^ 0u ^ 42u;   // 0x1BD11BF0

    uint32_t x0 = 0u + ks0;
    uint32_t x1 = ctr + ks1;

    // group 0: rotations 13,15,26,6
    x0 += x1; x1 = rotl32(x1, 13); x1 ^= x0;
    x0 += x1; x1 = rotl32(x1, 15); x1 ^= x0;
    x0 += x1; x1 = rotl32(x1, 26); x1 ^= x0;
    x0 += x1; x1 = rotl32(x1,  6); x1 ^= x0;
    x0 += ks1; x1 += ks2 + 1u;
    // group 1: rotations 17,29,16,24
    x0 += x1; x1 = rotl32(x1, 17); x1 ^= x0;
    x0 += x1; x1 = rotl32(x1, 29); x1 ^= x0;
    x0 += x1; x1 = rotl32(x1, 16); x1 ^= x0;
    x0 += x1; x1 = rotl32(x1, 24); x1 ^= x0;
    x0 += ks2; x1 += ks0 + 2u;
    // group 2: rotations 13,15,26,6
    x0 += x1; x1 = rotl32(x1, 13); x1 ^= x0;
    x0 += x1; x1 = rotl32(x1, 15); x1 ^= x0;
    x0 += x1; x1 = rotl32(x1, 26); x1 ^= x0;
    x0 += x1; x1 = rotl32(x1,  6); x1 ^= x0;
    x0 += ks0; x1 += ks1 + 3u;
    // group 3: rotations 17,29,16,24
    x0 += x1; x1 = rotl32(x1, 17); x1 ^= x0;
    x0 += x1; x1 = rotl32(x1, 29); x1 ^= x0;
    x0 += x1; x1 = rotl32(x1, 16); x1 ^= x0;
    x0 += x1; x1 = rotl32(x1, 24); x1 ^= x0;
    x0 += ks1; x1 += ks2 + 4u;
    // group 4: rotations 13,15,26,6
    x0 += x1; x1 = rotl32(x1, 13); x1 ^= x0;
    x0 += x1; x1 = rotl32(x1, 15); x1 ^= x0;
    x0 += x1; x1 = rotl32(x1, 26); x1 ^= x0;
    x0 += x1; x1 = rotl32(x1,  6); x1 ^= x0;
    x0 += ks2; x1 += ks0 + 5u;

    return x0 ^ x1;
}

// Ordering-equivalent gumbel score in the log2 domain:
//   z = l + g,  g = -ln(-ln u)  ==>  z/ln2 = l*(1/ln2) - log2(-log2 u) + const.
// Relative accuracy where winners live (u->1): degree-7 Taylor in w=u-1 for
// u in [0.875,1) (truncation <= 6.4e-8 rel); hw v_log_f32 elsewhere (t>=0.19,
// absolute ~1e-6 is fine there).
// Micro-cuts vs prev round: no fmaxf(tiny) — m=0 gives u=0 -> th=+inf ->
// lg=+inf -> score=-inf, same loser-ordering as the reference's u=tiny loser
// (flip needs m==0 AND row-winner: probability ~0). w computed as v1-2 (exact),
// poly/hw select via integer mantissa compare (m already live).
__device__ __forceinline__ float score_from_bits(uint32_t bits, float logit) {
    const uint32_t m  = bits >> 9;
    const float    v1 = __uint_as_float(m | 0x3f800000u);   // [1,2)
    const float    u  = v1 - 1.0f;                          // [0,1) exact
    const float    w  = v1 - 2.0f;                          // = u-1, exact
    // Q(w) = (1/ln2)*(-1 + w/2 - w^2/3 + w^3/4 - w^4/5 + w^5/6 - w^6/7)
    float q;
    q = fmaf(w, -0.20609929f,  0.24044917f);
    q = fmaf(w, q, -0.28853901f);
    q = fmaf(w, q,  0.36067376f);
    q = fmaf(w, q, -0.48089835f);
    q = fmaf(w, q,  0.72134752f);
    q = fmaf(w, q, -1.44269504f);
    const float tp = w * q;                                 // -log2(u), u near 1
    const float th = -__builtin_amdgcn_logf(u);             // -log2(u), hw path
    const float t  = (m >= 0x00700000u) ? tp : th;          // u>=0.875 ? poly : hw
    const float lg = __builtin_amdgcn_logf(t);              // log2(-log2 u)
    return fmaf(logit, 1.44269504f, -lg);                   // z' = l/ln2 - lg
}

// 256 threads = 4 waves; each wave owns ONE row (64 lanes x 16 elements).
// No LDS, no __syncthreads: shfl_xor butterfly reduction, all lanes converge.
// 4 independent accumulator pairs break the serial per-element dependency
// chain (prev build: VGPR=12 => compiler serialized everything; threefry is a
// pure dep chain, so waves issued at ~half rate).
__global__ __launch_bounds__(256) void gumbel_argmax_gather(
    const float* __restrict__ logits,
    const float* __restrict__ prim,
    float* __restrict__ out)
{
    const int tid  = threadIdx.x;
    const int lane = tid & 63;
    const int wv   = tid >> 6;
    const int row  = (blockIdx.x << 2) + wv;           // 8192 blocks * 4 rows
    const uint32_t base = (uint32_t)row * (uint32_t)KDIM;

    float bv[4] = {-INFINITY, -INFINITY, -INFINITY, -INFINITY};
    int   bk[4] = {0, 0, 0, 0};

    #pragma unroll
    for (int j = 0; j < 4; ++j) {
        const uint32_t k0 = (uint32_t)(j * 256 + lane * 4);  // coalesced 1KB/load
        const float4 l4 = *reinterpret_cast<const float4*>(logits + base + k0);
        const float lv[4] = {l4.x, l4.y, l4.z, l4.w};
        #pragma unroll
        for (int mm = 0; mm < 4; ++mm) {
            const float z = score_from_bits(threefry_bits(base + k0 + (uint32_t)mm),
                                            lv[mm]);
            // per-accumulator: j ascending => k ascending, strict > keeps first
            if (z > bv[mm]) { bv[mm] = z; bk[mm] = (int)(k0 + (uint32_t)mm); }
        }
    }

    // combine the 4 accumulators, first-index tie-break
    float v = bv[0]; int kk = bk[0];
    #pragma unroll
    for (int mm = 1; mm < 4; ++mm) {
        if (bv[mm] > v || (bv[mm] == v && bk[mm] < kk)) { v = bv[mm]; kk = bk[mm]; }
    }

    // wave butterfly (all 64 lanes converge to the row winner)
    #pragma unroll
    for (int off = 1; off < 64; off <<= 1) {
        const float ov = __shfl_xor(v, off);
        const int   ok = __shfl_xor(kk, off);
        if (ov > v || (ov == v && ok < kk)) { v = ov; kk = ok; }
    }

    if (lane == 0) {
        out[IDX_OFF + row] = (float)kk;            // indices stored as f32 values
        atomicAdd(out + CNT_OFF + kk, 1.0f);       // exact integer accum in f32
    }

    // gather primitives[kk] -> embeddings row (float4, coalesced, wave-private)
    const float4* __restrict__ src = (const float4*)(prim + (size_t)kk * KDIM);
    float4* __restrict__ dst = (float4*)(out + (size_t)row * KDIM);
    #pragma unroll
    for (int it = 0; it < 4; ++it) {
        dst[it * 64 + lane] = src[it * 64 + lane];
    }
}

extern "C" void kernel_launch(void* const* d_in, const int* in_sizes, int n_in,
                              void* d_out, int out_size, void* d_ws, size_t ws_size,
                              hipStream_t stream) {
    const float* logits = (const float*)d_in[0];   // [8,4096,1024] f32
    const float* prim   = (const float*)d_in[1];   // [1024,1024]   f32
    float* out = (float*)d_out;
    (void)d_ws; (void)ws_size; (void)in_sizes; (void)n_in; (void)out_size;

    // counts accumulate via f32 atomics directly in the output region:
    // zero it every launch (graph-safe), single fused kernel.
    hipMemsetAsync(out + CNT_OFF, 0, KDIM * sizeof(float), stream);
    gumbel_argmax_gather<<<NROWS / 4, 256, 0, stream>>>(logits, prim, out);
}